// Round 1
// baseline (764.253 us; speedup 1.0000x reference)
//
#include <hip/hip_runtime.h>
#include <math.h>

#define P 13
#define ROWS_PER_BLOCK 256
#define THREADS 256
#define TILE_ELEMS (ROWS_PER_BLOCK * P)        // 3328 floats
#define TILE_VEC4 (TILE_ELEMS / 4)             // 832 float4

__global__ __launch_bounds__(THREADS)
void chordal_softmax_kernel(const float* __restrict__ x,
                            const float* __restrict__ w,
                            float* __restrict__ out,
                            long long nrows) {
    __shared__ float tile[TILE_ELEMS];
    __shared__ float wperm[12 * P];            // permuted weight per root_pc

    const int tid = threadIdx.x;

    // Build the 12x13 permuted-weight table once per block.
    // wperm[r][j] = w[(j - r) mod 12] for j<12; w[12] for j==12.
    if (tid < 12 * P) {
        int r = tid / P;
        int j = tid - r * P;
        wperm[tid] = (j < 12) ? w[(j + 12 - r) % 12] : w[12];
    }

    const long long base = (long long)blockIdx.x * TILE_ELEMS;
    const long long total = nrows * P;

    // ---- Stage global -> LDS (coalesced float4) ----
    if (base + TILE_ELEMS <= total) {
        const float4* in4 = reinterpret_cast<const float4*>(x + base);
        float4* tile4 = reinterpret_cast<float4*>(tile);
        #pragma unroll
        for (int i = 0; i < 4; ++i) {
            int idx = tid + i * THREADS;
            if (idx < TILE_VEC4) tile4[idx] = in4[idx];
        }
    } else {
        // tail block (not hit for this problem size, kept for safety)
        for (int idx = tid; idx < TILE_ELEMS; idx += THREADS) {
            long long g = base + idx;
            if (g < total) tile[idx] = x[g];
        }
    }
    __syncthreads();   // also publishes wperm

    // ---- Per-thread row softmax ----
    const long long row = (long long)blockIdx.x * ROWS_PER_BLOCK + tid;
    if (row < nrows) {
        const int label = (int)(row % 144);
        const int root = label / 12;           // 0..11
        const float* wp = &wperm[root * P];

        float v[P];
        float m = -1e30f;
        #pragma unroll
        for (int j = 0; j < P; ++j) {
            v[j] = tile[tid * P + j] * wp[j];
            m = fmaxf(m, v[j]);
        }
        float s = 0.0f;
        #pragma unroll
        for (int j = 0; j < P; ++j) {
            v[j] = __expf(v[j] - m);
            s += v[j];
        }
        const float inv = 1.0f / s;
        #pragma unroll
        for (int j = 0; j < P; ++j) {
            tile[tid * P + j] = v[j] * inv;
        }
    }
    __syncthreads();

    // ---- Stage LDS -> global (coalesced float4) ----
    if (base + TILE_ELEMS <= total) {
        float4* out4 = reinterpret_cast<float4*>(out + base);
        const float4* tile4 = reinterpret_cast<const float4*>(tile);
        #pragma unroll
        for (int i = 0; i < 4; ++i) {
            int idx = tid + i * THREADS;
            if (idx < TILE_VEC4) out4[idx] = tile4[idx];
        }
    } else {
        for (int idx = tid; idx < TILE_ELEMS; idx += THREADS) {
            long long g = base + idx;
            if (g < total) out[g] = tile[idx];
        }
    }
}

extern "C" void kernel_launch(void* const* d_in, const int* in_sizes, int n_in,
                              void* d_out, int out_size, void* d_ws, size_t ws_size,
                              hipStream_t stream) {
    const float* x = (const float*)d_in[0];   // [B, L, P] f32
    const float* w = (const float*)d_in[1];   // [P] f32
    float* out = (float*)d_out;               // [B, L, P] f32

    const long long total = (long long)in_sizes[0];
    const long long nrows = total / P;        // B*L = 9,437,184
    const int blocks = (int)((nrows + ROWS_PER_BLOCK - 1) / ROWS_PER_BLOCK);

    chordal_softmax_kernel<<<blocks, THREADS, 0, stream>>>(x, w, out, nrows);
}